// Round 4
// baseline (56.099 us; speedup 1.0000x reference)
//
#include <hip/hip_runtime.h>
#include <hip/hip_bf16.h>

#define B_ 32
#define L_ 512
#define H_ 1024
#define E_ 8
#define R_ 16

typedef float f32x4 __attribute__((ext_vector_type(4)));
typedef __bf16 bf16x8 __attribute__((ext_vector_type(8)));
typedef __bf16 bf16x4 __attribute__((ext_vector_type(4)));

static __device__ __forceinline__ __bf16 f2b(float f) { return (__bf16)f; }

// Fully fused: gates + D = X Wd^T (MFMA) + out = x + (gD) U (MFMA).
// LDS plan: xs (bf16 X tile, 33 KB) lives only in phase A; the reduction
// buffer + gated-D tile are UNIONed on top of it -> 33 KB total -> 4 blocks/CU.
__global__ __launch_bounds__(256, 4) void moe_fused_kernel(
    const float* __restrict__ x, const float* __restrict__ rw,
    const float* __restrict__ ldown, const float* __restrict__ lup,
    float* __restrict__ out)
{
  constexpr int LT = 16;
  constexpr int XW = 1032;                    // bf16 row stride (pad 8 -> 2-way max)

  __shared__ union {
    __bf16 xs[LT][XW];                        // 33,024 B  (phase A only)
    struct {
      f32x4  red[4][2][64];                   // 8,192 B   (cross-wave K reduce)
      __bf16 dg[16][40];                      // 1,280 B   (gated D, bf16)
    } p2;
  } sm;
  __shared__ float logits[E_];
  __shared__ float gv[2];
  __shared__ int   ge[2];

  const int t    = threadIdx.x;
  const int w    = t >> 6;
  const int lane = t & 63;
  const int gq   = lane >> 4;                 // 0..3
  const int r16  = lane & 15;

  const int b  = blockIdx.x >> 5;
  const int l0 = (blockIdx.x & 31) * LT;

  const float* xb = x + ((size_t)b * L_ + l0) * H_;

  // ---- stage X tile: f32 coalesced loads -> bf16 -> LDS (issues first) ----
  {
    const int srow = t >> 4;
    const int sc0  = (t & 15) * 4;
    const float* xr = xb + (size_t)srow * H_ + sc0;
#pragma unroll
    for (int i = 0; i < 16; ++i) {
      float4 v = *(const float4*)(xr + i * 64);
      bf16x4 bv = { f2b(v.x), f2b(v.y), f2b(v.z), f2b(v.w) };
      *(bf16x4*)&sm.xs[srow][sc0 + i * 64] = bv;
    }
  }

  // ---- gates (redundant per block; x[b,0,:] + router_w are cache-resident) -
  {
    const int e = t >> 5, s = t & 31;
    const float* cls = x + (size_t)b * L_ * H_;
    const float* wr  = rw + (size_t)e * H_;
    float p = 0.f;
    for (int h = s; h < H_; h += 32) p += cls[h] * wr[h];
#pragma unroll
    for (int off = 16; off; off >>= 1) p += __shfl_down(p, off, 32);
    if (s == 0) logits[e] = p;
  }
  __syncthreads();                            // logits visible
  if (t == 0) {
    float m0 = -1e30f; int i0 = 0;
    for (int j = 0; j < E_; ++j) if (logits[j] > m0) { m0 = logits[j]; i0 = j; }
    float m1 = -1e30f; int i1 = 0;
    for (int j = 0; j < E_; ++j) if (j != i0 && logits[j] > m1) { m1 = logits[j]; i1 = j; }
    float eb = expf(m1 - m0), inv = 1.f / (1.f + eb);
    gv[0] = inv; gv[1] = eb * inv; ge[0] = i0; ge[1] = i1;
  }
  __syncthreads();                            // xs + gv/ge ready

  const float g0 = gv[0], g1 = gv[1];
  const int   e0 = ge[0], e1 = ge[1];

  // ---- Phase A: D[16][32] = X(16xK) * Wd^T, K split across 4 waves --------
  const float* w0p = ldown + (size_t)(e0 * R_ + r16) * H_;    // B-frag n = r16
  const float* w1p = ldown + (size_t)(e1 * R_ + r16) * H_;

  f32x4 acc0 = {0.f, 0.f, 0.f, 0.f};
  f32x4 acc1 = {0.f, 0.f, 0.f, 0.f};

#pragma unroll 4
  for (int s = 0; s < 8; ++s) {
    const int kb = w * 256 + s * 32;
    const int kl = kb + 4 * gq;               // k of elems 0..3
    const int kh = kl + 16;                   // k of elems 4..7
    bf16x4 xlo = *(const bf16x4*)&sm.xs[r16][kl];   // ds_read_b64, conflict-free
    bf16x4 xhi = *(const bf16x4*)&sm.xs[r16][kh];
    float4 alo = *(const float4*)(w0p + kl);
    float4 ahi = *(const float4*)(w0p + kh);
    float4 blo = *(const float4*)(w1p + kl);
    float4 bhi = *(const float4*)(w1p + kh);
    bf16x8 af  = { xlo[0], xlo[1], xlo[2], xlo[3], xhi[0], xhi[1], xhi[2], xhi[3] };
    bf16x8 bf0 = { f2b(alo.x), f2b(alo.y), f2b(alo.z), f2b(alo.w),
                   f2b(ahi.x), f2b(ahi.y), f2b(ahi.z), f2b(ahi.w) };
    bf16x8 bf1 = { f2b(blo.x), f2b(blo.y), f2b(blo.z), f2b(blo.w),
                   f2b(bhi.x), f2b(bhi.y), f2b(bhi.z), f2b(bhi.w) };
    acc0 = __builtin_amdgcn_mfma_f32_16x16x32_bf16(af, bf0, acc0, 0, 0, 0);
    acc1 = __builtin_amdgcn_mfma_f32_16x16x32_bf16(af, bf1, acc1, 0, 0, 0);
  }

  __syncthreads();                            // all waves done READING xs
  sm.p2.red[w][0][lane] = acc0;               // safe: union region reused
  sm.p2.red[w][1][lane] = acc1;
  __syncthreads();

  // ---- cross-wave reduce + gate fold + bf16 pack of D ---------------------
  if (t < 128) {
    const int tile = t >> 6;                  // 0: e0 cols, 1: e1 cols
    const int slot = t & 63;
    f32x4 v = sm.p2.red[0][tile][slot];
    v += sm.p2.red[1][tile][slot];
    v += sm.p2.red[2][tile][slot];
    v += sm.p2.red[3][tile][slot];
    const float g = tile ? g1 : g0;
    const int p  = tile * 16 + (slot & 15);   // C/D: col = lane&15
    const int r0 = (slot >> 4) * 4;           // C/D: row = 4*(lane>>4)+j
#pragma unroll
    for (int j = 0; j < 4; ++j) sm.p2.dg[r0 + j][p] = f2b(v[j] * g);
  }
  __syncthreads();

  // ---- Phase B: out[16][1024] = x + Dg(16x32) * Up(32x1024) ---------------
  bf16x8 dfrag;
  {
    const int kl = 4 * gq;
#pragma unroll
    for (int j = 0; j < 4; ++j) {
      dfrag[j]     = sm.p2.dg[r16][kl + j];
      dfrag[4 + j] = sm.p2.dg[r16][16 + kl + j];
    }
  }

  const float* u0b = lup + (size_t)e0 * H_ * R_;
  const float* u1b = lup + (size_t)e1 * H_ * R_;
  float* outb = out + ((size_t)b * L_ + l0) * H_;

#pragma unroll 4
  for (int nt = 0; nt < 16; ++nt) {
    const int h = w * 256 + nt * 16 + r16;    // B-frag col = r16
    float4 ulo = *(const float4*)(u0b + (size_t)h * R_ + 4 * gq);
    float4 uhi = *(const float4*)(u1b + (size_t)h * R_ + 4 * gq);
    bf16x8 uf = { f2b(ulo.x), f2b(ulo.y), f2b(ulo.z), f2b(ulo.w),
                  f2b(uhi.x), f2b(uhi.y), f2b(uhi.z), f2b(uhi.w) };
    f32x4 acc;
#pragma unroll
    for (int j = 0; j < 4; ++j)               // exact f32 residual, L2-hit re-read
      acc[j] = xb[(size_t)(4 * gq + j) * H_ + h];
    acc = __builtin_amdgcn_mfma_f32_16x16x32_bf16(dfrag, uf, acc, 0, 0, 0);
#pragma unroll
    for (int j = 0; j < 4; ++j) outb[(size_t)(4 * gq + j) * H_ + h] = acc[j];
  }
}

extern "C" void kernel_launch(void* const* d_in, const int* in_sizes, int n_in,
                              void* d_out, int out_size, void* d_ws, size_t ws_size,
                              hipStream_t stream) {
  const float* x  = (const float*)d_in[0];
  const float* rw = (const float*)d_in[1];
  const float* ld = (const float*)d_in[2];
  const float* lu = (const float*)d_in[3];
  float* outp = (float*)d_out;

  hipLaunchKernelGGL(moe_fused_kernel, dim3(B_ * (L_ / 16)), dim3(256), 0, stream,
                     x, rw, ld, lu, outp);
}

// Round 5
// 48.723 us; speedup vs baseline: 1.1514x; 1.1514x over previous
//
#include <hip/hip_runtime.h>
#include <hip/hip_bf16.h>

#define B_ 32
#define L_ 512
#define H_ 1024
#define E_ 8
#define R_ 16

typedef float f32x4 __attribute__((ext_vector_type(4)));
typedef __bf16 bf16x8 __attribute__((ext_vector_type(8)));
typedef __bf16 bf16x4 __attribute__((ext_vector_type(4)));

static __device__ __forceinline__ __bf16 f2b(float f) { return (__bf16)f; }

// Fused: gates + D = X Wd^T (MFMA) + out = x + (gD) U (MFMA, transposed tile).
// xs (bf16 X tile) stays alive the whole kernel: phase-A A-frags AND the
// phase-B residual come from LDS -> x is read from global exactly once.
// LDS ~42.5 KB -> 3 blocks/CU.
__global__ __launch_bounds__(256, 3) void moe_fused_kernel(
    const float* __restrict__ x, const float* __restrict__ rw,
    const float* __restrict__ ldown, const float* __restrict__ lup,
    float* __restrict__ out)
{
  constexpr int LT = 16;
  constexpr int XW = 1032;                  // bf16 row stride (pad 8)

  __shared__ __bf16 xs[LT][XW];             // 33,024 B, alive all kernel
  __shared__ f32x4  red[4][2][64];          // 8,192 B  cross-wave K reduce
  __shared__ __bf16 dg[16][40];             // 1,280 B  gated D (bf16)
  __shared__ float logits[E_];
  __shared__ float gv[2];
  __shared__ int   ge[2];

  const int t    = threadIdx.x;
  const int w    = t >> 6;
  const int lane = t & 63;
  const int gq   = lane >> 4;               // 0..3
  const int r16  = lane & 15;

  const int b  = blockIdx.x >> 5;
  const int l0 = (blockIdx.x & 31) * LT;

  const float* xb = x + ((size_t)b * L_ + l0) * H_;

  // ---- stage X tile: f32 coalesced loads -> bf16 -> LDS -------------------
  {
    const int srow = t >> 4;
    const int sc0  = (t & 15) * 4;
    const float* xr = xb + (size_t)srow * H_ + sc0;
#pragma unroll
    for (int i = 0; i < 16; ++i) {
      float4 v = *(const float4*)(xr + i * 64);
      bf16x4 bv = { f2b(v.x), f2b(v.y), f2b(v.z), f2b(v.w) };
      *(bf16x4*)&xs[srow][sc0 + i * 64] = bv;
    }
  }

  // ---- gates (per-block redundant; float4 dot, 8 iters) -------------------
  {
    const int e = t >> 5, s = t & 31;
    const float* cls = x + (size_t)b * L_ * H_;   // x[b,0,:]
    const float* wr  = rw + (size_t)e * H_;
    float p = 0.f;
#pragma unroll
    for (int c = s; c < 256; c += 32) {
      float4 xv = *(const float4*)(cls + 4 * c);
      float4 wv = *(const float4*)(wr + 4 * c);
      p += xv.x * wv.x + xv.y * wv.y + xv.z * wv.z + xv.w * wv.w;
    }
#pragma unroll
    for (int off = 16; off; off >>= 1) p += __shfl_down(p, off, 32);
    if (s == 0) logits[e] = p;
  }
  __syncthreads();                          // logits + xs visible
  if (t == 0) {
    float m0 = -1e30f; int i0 = 0;
    for (int j = 0; j < E_; ++j) if (logits[j] > m0) { m0 = logits[j]; i0 = j; }
    float m1 = -1e30f; int i1 = 0;
    for (int j = 0; j < E_; ++j) if (j != i0 && logits[j] > m1) { m1 = logits[j]; i1 = j; }
    float eb = expf(m1 - m0), inv = 1.f / (1.f + eb);
    gv[0] = inv; gv[1] = eb * inv; ge[0] = i0; ge[1] = i1;
  }
  __syncthreads();

  const float g0 = gv[0], g1 = gv[1];
  const int   e0 = ge[0], e1 = ge[1];

  // ---- Phase A: D[16][32] = X(16xK) * Wd^T, K split across 4 waves --------
  const float* w0p = ldown + (size_t)(e0 * R_ + r16) * H_;   // B-frag n = r16
  const float* w1p = ldown + (size_t)(e1 * R_ + r16) * H_;

  f32x4 acc0 = {0.f, 0.f, 0.f, 0.f};
  f32x4 acc1 = {0.f, 0.f, 0.f, 0.f};

#pragma unroll 4
  for (int s = 0; s < 8; ++s) {
    const int kb = w * 256 + s * 32;
    const int kl = kb + 4 * gq;             // k of elems 0..3
    const int kh = kl + 16;                 // k of elems 4..7
    bf16x4 xlo = *(const bf16x4*)&xs[r16][kl];
    bf16x4 xhi = *(const bf16x4*)&xs[r16][kh];
    float4 alo = *(const float4*)(w0p + kl);
    float4 ahi = *(const float4*)(w0p + kh);
    float4 blo = *(const float4*)(w1p + kl);
    float4 bhi = *(const float4*)(w1p + kh);
    bf16x8 af  = { xlo[0], xlo[1], xlo[2], xlo[3], xhi[0], xhi[1], xhi[2], xhi[3] };
    bf16x8 bf0 = { f2b(alo.x), f2b(alo.y), f2b(alo.z), f2b(alo.w),
                   f2b(ahi.x), f2b(ahi.y), f2b(ahi.z), f2b(ahi.w) };
    bf16x8 bf1 = { f2b(blo.x), f2b(blo.y), f2b(blo.z), f2b(blo.w),
                   f2b(bhi.x), f2b(bhi.y), f2b(bhi.z), f2b(bhi.w) };
    acc0 = __builtin_amdgcn_mfma_f32_16x16x32_bf16(af, bf0, acc0, 0, 0, 0);
    acc1 = __builtin_amdgcn_mfma_f32_16x16x32_bf16(af, bf1, acc1, 0, 0, 0);
  }

  red[w][0][lane] = acc0;
  red[w][1][lane] = acc1;

  // prefetch nt=0 U-frags (independent of dg) to hide reduce-barrier latency
  const float* u0b = lup + (size_t)e0 * H_ * R_;
  const float* u1b = lup + (size_t)e1 * H_ * R_;
  float4 ulo = *(const float4*)(u0b + (size_t)(w * 256 + r16) * R_ + 4 * gq);
  float4 uhi = *(const float4*)(u1b + (size_t)(w * 256 + r16) * R_ + 4 * gq);

  __syncthreads();

  // ---- cross-wave reduce + gate fold + bf16 pack of D ---------------------
  if (t < 128) {
    const int tile = t >> 6;                // 0: e0 cols, 1: e1 cols
    const int slot = t & 63;
    f32x4 v = red[0][tile][slot];
    v += red[1][tile][slot];
    v += red[2][tile][slot];
    v += red[3][tile][slot];
    const float g = tile ? g1 : g0;
    const int p  = tile * 16 + (slot & 15); // C/D: col = lane&15
    const int r0 = (slot >> 4) * 4;         // C/D: row = 4*(lane>>4)+j
#pragma unroll
    for (int j = 0; j < 4; ++j) dg[r0 + j][p] = f2b(v[j] * g);
  }
  __syncthreads();

  // ---- Phase B (transposed tile): out^T[h][l] = x^T + U^T(16x32) Dg^T -----
  // A-frag = U^T: lane row h = h0+r16, k=p=4gq+j (lo: e0, hi: e1)
  // B-frag = Dg^T: lane col l = r16, k=p       -> same dfrag as before
  // D-frag: lane holds out[l=r16][h0+4gq+j], j=0..3 -> float4 store
  bf16x8 dfrag;
  {
#pragma unroll
    for (int j = 0; j < 4; ++j) {
      dfrag[j]     = dg[r16][4 * gq + j];
      dfrag[4 + j] = dg[r16][16 + 4 * gq + j];
    }
  }

  float* outr = out + ((size_t)b * L_ + l0 + r16) * H_;   // this lane's row

#pragma unroll 1
  for (int nt = 0; nt < 16; ++nt) {
    const float4 culo = ulo, cuhi = uhi;
    if (nt < 15) {                          // rotate: prefetch next U-frags
      const int hn = w * 256 + (nt + 1) * 16 + r16;
      ulo = *(const float4*)(u0b + (size_t)hn * R_ + 4 * gq);
      uhi = *(const float4*)(u1b + (size_t)hn * R_ + 4 * gq);
    }
    bf16x8 uf = { f2b(culo.x), f2b(culo.y), f2b(culo.z), f2b(culo.w),
                  f2b(cuhi.x), f2b(cuhi.y), f2b(cuhi.z), f2b(cuhi.w) };
    const int h0 = w * 256 + nt * 16;
    bf16x4 rx = *(const bf16x4*)&xs[r16][h0 + 4 * gq];    // residual (bf16)
    f32x4 acc = { (float)rx[0], (float)rx[1], (float)rx[2], (float)rx[3] };
    acc = __builtin_amdgcn_mfma_f32_16x16x32_bf16(uf, dfrag, acc, 0, 0, 0);
    *(float4*)(outr + h0 + 4 * gq) = *(float4*)&acc;
  }
}

extern "C" void kernel_launch(void* const* d_in, const int* in_sizes, int n_in,
                              void* d_out, int out_size, void* d_ws, size_t ws_size,
                              hipStream_t stream) {
  const float* x  = (const float*)d_in[0];
  const float* rw = (const float*)d_in[1];
  const float* ld = (const float*)d_in[2];
  const float* lu = (const float*)d_in[3];
  float* outp = (float*)d_out;

  hipLaunchKernelGGL(moe_fused_kernel, dim3(B_ * (L_ / 16)), dim3(256), 0, stream,
                     x, rw, ld, lu, outp);
}

// Round 6
// 47.297 us; speedup vs baseline: 1.1861x; 1.0302x over previous
//
#include <hip/hip_runtime.h>
#include <hip/hip_bf16.h>

#define B_ 32
#define L_ 512
#define H_ 1024
#define E_ 8
#define R_ 16

typedef float f32x4 __attribute__((ext_vector_type(4)));
typedef __bf16 bf16x8 __attribute__((ext_vector_type(8)));

static __device__ __forceinline__ __bf16 f2b(float f) { return (__bf16)f; }

#define GLB_AS(p) ((const __attribute__((address_space(1))) void*)(p))
#define LDS_AS(p) ((__attribute__((address_space(3))) void*)(p))

// Fused: gates + D = X Wd^T (MFMA) + out = x + (gD) U (MFMA, transposed tile).
// X tile staged as f32 via async global_load_lds (fire-and-forget, no VGPR
// round-trip). LDS dest is linear (HW requirement); bank conflicts avoided by
// pre-swizzling the GLOBAL source address with byte^=(row&7)<<4 and applying
// the same XOR on all LDS reads (T2/m173 pattern). Residual is exact f32.
__global__ __launch_bounds__(256, 2) void moe_fused_kernel(
    const float* __restrict__ x, const float* __restrict__ rw,
    const float* __restrict__ ldown, const float* __restrict__ lup,
    float* __restrict__ out)
{
  __shared__ float  xs[16 * 1024];          // 64 KB f32, swizzled storage
  __shared__ f32x4  red[4][2][64];          // 8 KB cross-wave K reduce
  __shared__ __bf16 dg[16][40];             // gated D (bf16)
  __shared__ float  logits[E_];
  __shared__ float  gv[2];
  __shared__ int    ge[2];

  const int t    = threadIdx.x;
  const int w    = t >> 6;
  const int lane = t & 63;
  const int gq   = lane >> 4;               // 0..3
  const int r16  = lane & 15;

  const int b  = blockIdx.x >> 5;
  const int l0 = (blockIdx.x & 31) * 16;

  const float* xb = x + ((size_t)b * L_ + l0) * H_;

  // ---- stage X tile: 16 async global->LDS (16B/lane), source pre-swizzled -
  {
#pragma unroll
    for (int i = 0; i < 16; ++i) {
      const int row = 4 * w + (i >> 2);
      const unsigned phys = (unsigned)(((i & 3) << 10) | (lane << 4));
      const unsigned src  = phys ^ (unsigned)((row & 7) << 4);
      const char* g = (const char*)(xb + (size_t)row * H_) + src;
      char* l = (char*)xs + (w << 14) + (i << 10);   // wave-uniform; HW adds lane*16
      __builtin_amdgcn_global_load_lds(GLB_AS(g), LDS_AS(l), 16, 0, 0);
    }
  }

  // ---- gates (per-block redundant; float4 dot over x[b,0,:]) --------------
  {
    const int e = t >> 5, s = t & 31;
    const float* cls = x + (size_t)b * L_ * H_;
    const float* wr  = rw + (size_t)e * H_;
    float p = 0.f;
#pragma unroll
    for (int c = s; c < 256; c += 32) {
      float4 xv = *(const float4*)(cls + 4 * c);
      float4 wv = *(const float4*)(wr + 4 * c);
      p += xv.x * wv.x + xv.y * wv.y + xv.z * wv.z + xv.w * wv.w;
    }
#pragma unroll
    for (int off = 16; off; off >>= 1) p += __shfl_down(p, off, 32);
    if (s == 0) logits[e] = p;
  }
  __syncthreads();                          // drains staging vmcnt too
  if (t == 0) {
    float m0 = -1e30f; int i0 = 0;
    for (int j = 0; j < E_; ++j) if (logits[j] > m0) { m0 = logits[j]; i0 = j; }
    float m1 = -1e30f; int i1 = 0;
    for (int j = 0; j < E_; ++j) if (j != i0 && logits[j] > m1) { m1 = logits[j]; i1 = j; }
    float eb = expf(m1 - m0), inv = 1.f / (1.f + eb);
    gv[0] = inv; gv[1] = eb * inv; ge[0] = i0; ge[1] = i1;
  }
  __syncthreads();                          // xs + gates ready

  const float g0 = gv[0], g1 = gv[1];
  const int   e0 = ge[0], e1 = ge[1];

  const unsigned swzr = (unsigned)((r16 & 7) << 4);
  const char* xrow = (const char*)xs + (r16 << 12);   // this lane's swizzled row

  // ---- Phase A: D[16][32] = X(16xK) * Wd^T, K split across 4 waves --------
  const float* w0p = ldown + (size_t)(e0 * R_ + r16) * H_;   // B-frag n = r16
  const float* w1p = ldown + (size_t)(e1 * R_ + r16) * H_;

  f32x4 acc0 = {0.f, 0.f, 0.f, 0.f};
  f32x4 acc1 = {0.f, 0.f, 0.f, 0.f};

#pragma unroll 4
  for (int s = 0; s < 8; ++s) {
    const int kl = w * 256 + s * 32 + 4 * gq;         // k of elems 0..3
    const unsigned cb = (unsigned)(kl << 2);          // byte within row
    float4 xlo = *(const float4*)(xrow + (cb ^ swzr));
    float4 xhi = *(const float4*)(xrow + ((cb + 64) ^ swzr));
    float4 alo = *(const float4*)(w0p + kl);
    float4 ahi = *(const float4*)(w0p + kl + 16);
    float4 blo = *(const float4*)(w1p + kl);
    float4 bhi = *(const float4*)(w1p + kl + 16);
    bf16x8 af  = { f2b(xlo.x), f2b(xlo.y), f2b(xlo.z), f2b(xlo.w),
                   f2b(xhi.x), f2b(xhi.y), f2b(xhi.z), f2b(xhi.w) };
    bf16x8 bf0 = { f2b(alo.x), f2b(alo.y), f2b(alo.z), f2b(alo.w),
                   f2b(ahi.x), f2b(ahi.y), f2b(ahi.z), f2b(ahi.w) };
    bf16x8 bf1 = { f2b(blo.x), f2b(blo.y), f2b(blo.z), f2b(blo.w),
                   f2b(bhi.x), f2b(bhi.y), f2b(bhi.z), f2b(bhi.w) };
    acc0 = __builtin_amdgcn_mfma_f32_16x16x32_bf16(af, bf0, acc0, 0, 0, 0);
    acc1 = __builtin_amdgcn_mfma_f32_16x16x32_bf16(af, bf1, acc1, 0, 0, 0);
  }

  red[w][0][lane] = acc0;
  red[w][1][lane] = acc1;

  // prefetch nt=0 U-frags (independent of dg) to hide reduce-barrier latency
  const float* u0b = lup + (size_t)e0 * H_ * R_;
  const float* u1b = lup + (size_t)e1 * H_ * R_;
  float4 ulo = *(const float4*)(u0b + (size_t)(w * 256 + r16) * R_ + 4 * gq);
  float4 uhi = *(const float4*)(u1b + (size_t)(w * 256 + r16) * R_ + 4 * gq);

  __syncthreads();

  // ---- cross-wave reduce + gate fold + bf16 pack of D ---------------------
  if (t < 128) {
    const int tile = t >> 6;                // 0: e0 cols, 1: e1 cols
    const int slot = t & 63;
    f32x4 v = red[0][tile][slot];
    v += red[1][tile][slot];
    v += red[2][tile][slot];
    v += red[3][tile][slot];
    const float g = tile ? g1 : g0;
    const int p  = tile * 16 + (slot & 15); // C/D: col = lane&15
    const int r0 = (slot >> 4) * 4;         // C/D: row = 4*(lane>>4)+j
#pragma unroll
    for (int j = 0; j < 4; ++j) dg[r0 + j][p] = f2b(v[j] * g);
  }
  __syncthreads();

  // ---- Phase B (transposed tile): out^T[h][l] = x^T + U^T(16x32) Dg^T -----
  bf16x8 dfrag;
  {
#pragma unroll
    for (int j = 0; j < 4; ++j) {
      dfrag[j]     = dg[r16][4 * gq + j];
      dfrag[4 + j] = dg[r16][16 + 4 * gq + j];
    }
  }

  float* outr = out + ((size_t)b * L_ + l0 + r16) * H_;   // this lane's row

#pragma unroll 1
  for (int nt = 0; nt < 16; ++nt) {
    const float4 culo = ulo, cuhi = uhi;
    if (nt < 15) {                          // rotate: prefetch next U-frags
      const int hn = w * 256 + (nt + 1) * 16 + r16;
      ulo = *(const float4*)(u0b + (size_t)hn * R_ + 4 * gq);
      uhi = *(const float4*)(u1b + (size_t)hn * R_ + 4 * gq);
    }
    bf16x8 uf = { f2b(culo.x), f2b(culo.y), f2b(culo.z), f2b(culo.w),
                  f2b(cuhi.x), f2b(cuhi.y), f2b(cuhi.z), f2b(cuhi.w) };
    // exact f32 residual from swizzled LDS: row r16, cols h0+4gq..+3
    const unsigned cb = (unsigned)((w << 10) + (nt << 6) + (gq << 4));
    float4 rx = *(const float4*)(xrow + (cb ^ swzr));
    f32x4 acc = { rx.x, rx.y, rx.z, rx.w };
    acc = __builtin_amdgcn_mfma_f32_16x16x32_bf16(uf, dfrag, acc, 0, 0, 0);
    const int h0 = w * 256 + nt * 16;
    *(float4*)(outr + h0 + 4 * gq) = *(float4*)&acc;
  }
}

extern "C" void kernel_launch(void* const* d_in, const int* in_sizes, int n_in,
                              void* d_out, int out_size, void* d_ws, size_t ws_size,
                              hipStream_t stream) {
  const float* x  = (const float*)d_in[0];
  const float* rw = (const float*)d_in[1];
  const float* ld = (const float*)d_in[2];
  const float* lu = (const float*)d_in[3];
  float* outp = (float*)d_out;

  hipLaunchKernelGGL(moe_fused_kernel, dim3(B_ * (L_ / 16)), dim3(256), 0, stream,
                     x, rw, ld, lu, outp);
}